// Round 1
// baseline (241.075 us; speedup 1.0000x reference)
//
#include <hip/hip_runtime.h>
#include <hip/hip_bf16.h>

// B=2048, T=128, H=48, L=3. Gates G=192, K=2H=96.
// One WG (256 thr, 4 waves) per 8 batches -> 256 WGs, persistent over all 128 steps.
// Weights (bf16 B-fragments) live in registers; x|h in LDS (bf16); c in fp32 regs.

using bf16x8 = __attribute__((ext_vector_type(8))) __bf16;
using u16x8  = __attribute__((ext_vector_type(8))) unsigned short;
using f32x4  = __attribute__((ext_vector_type(4))) float;

__device__ __forceinline__ float fexp2(float x){ return __builtin_amdgcn_exp2f(x); }
__device__ __forceinline__ float frcp (float x){ return __builtin_amdgcn_rcpf(x); }
__device__ __forceinline__ float sigm (float x){ return frcp(1.f + fexp2(-1.44269504f*x)); }
__device__ __forceinline__ float tanha(float x){ return 1.f - 2.f*frcp(1.f + fexp2(2.88539008f*x)); }

__device__ __forceinline__ unsigned short f2bf(float x){
  unsigned u = __float_as_uint(x);
  return (unsigned short)((u + 0x7FFFu + ((u>>16)&1u)) >> 16);  // RNE
}

__device__ __forceinline__ f32x4 mfma16(u16x8 a, u16x8 b, f32x4 c){
  return __builtin_amdgcn_mfma_f32_16x16x32_bf16(
      __builtin_bit_cast(bf16x8, a), __builtin_bit_cast(bf16x8, b), c, 0, 0, 0);
}

__global__ __launch_bounds__(256, 1) void lstm_fused(
    const float* __restrict__ adj, const float* __restrict__ eps,
    const float* __restrict__ Wi,  const float* __restrict__ bi,
    const float* __restrict__ Wa,  const float* __restrict__ ba,
    const float* __restrict__ Wp,  const float* __restrict__ bp,
    const float* __restrict__ Wih, const float* __restrict__ Whh,
    const float* __restrict__ bih, const float* __restrict__ bhh,
    const float* __restrict__ h0,  const float* __restrict__ c0,
    float* __restrict__ out)
{
  const int tid  = threadIdx.x;
  const int wv   = tid >> 6;       // wave 0..3: owns gate columns 48*wv .. 48*wv+47
  const int lane = tid & 63;
  const int col  = lane & 15;      // MFMA n (gate) / m (batch row) index
  const int kg   = lane >> 4;      // k-group 0..3
  const int b0   = blockIdx.x * 8; // this WG's batches

  __shared__ __align__(16) unsigned short xh[3][8][112]; // [layer][b][ x(0..47) | h(48..95) | pad ], bf16 bits
  __shared__ __align__(16) float gbuf[192*12];           // gates fp32: [gate][b(8), row padded to 12]
  __shared__ float adjrow[8][128];
  __shared__ float epsrow[8][128];
  __shared__ float adjemb[8][48];
  __shared__ float h2f[8][52];
  __shared__ float WiS[48], biS[48], WpS[48];
  __shared__ float bpS;

  // ---- weight B-fragments -> registers (W^T combined [Wih|Whh], bf16) ----
  u16x8 wf[3][3][3];   // [layer][ktile][ntile] -- all indices compile-time after unroll
  float biasr[3][3];   // bih+bhh per (layer, ntile), splatted into acc init
#pragma unroll
  for (int l = 0; l < 3; ++l) {
#pragma unroll
    for (int kk = 0; kk < 3; ++kk) {
      const int k0 = 32*kk + 8*kg;                 // never straddles the 48 boundary
#pragma unroll
      for (int nt = 0; nt < 3; ++nt) {
        const int g = 48*wv + 16*nt + col;
        const float* src = (k0 < 48) ? (Wih + ((l*192 + g)*48 + k0))
                                     : (Whh + ((l*192 + g)*48 + (k0 - 48)));
        float4 p0 = *reinterpret_cast<const float4*>(src);
        float4 p1 = *reinterpret_cast<const float4*>(src + 4);
        u16x8 f;
        f[0]=f2bf(p0.x); f[1]=f2bf(p0.y); f[2]=f2bf(p0.z); f[3]=f2bf(p0.w);
        f[4]=f2bf(p1.x); f[5]=f2bf(p1.y); f[6]=f2bf(p1.z); f[7]=f2bf(p1.w);
        wf[l][kk][nt] = f;
      }
    }
#pragma unroll
    for (int nt = 0; nt < 3; ++nt) {
      const int g = 48*wv + 16*nt + col;
      biasr[l][nt] = bih[l*192 + g] + bhh[l*192 + g];
    }
  }

  // ---- stage adj/eps rows (8x128 each) + small vectors ----
  {
    const float4* ga = reinterpret_cast<const float4*>(adj + (size_t)b0*128);
    const float4* ge = reinterpret_cast<const float4*>(eps + (size_t)b0*128);
    reinterpret_cast<float4*>(&adjrow[0][0])[tid] = ga[tid];
    reinterpret_cast<float4*>(&epsrow[0][0])[tid] = ge[tid];
  }
  if (tid < 48) { WiS[tid] = Wi[tid]; biS[tid] = bi[tid]; WpS[tid] = Wp[tid]; }
  if (tid == 0) bpS = bp[0];
  __syncthreads();

  // ---- adj embedding (constant across steps): adjemb[b][j] = sum_t adj*Wa + ba ----
  for (int cid = tid; cid < 384; cid += 256) {
    const int b = cid & 7, j = cid >> 3;
    float s = ba[j];
    const float* wrow = Wa + j*128;
    for (int t = 0; t < 128; ++t) s += adjrow[b][t] * wrow[t];
    adjemb[b][j] = s;
  }
  // ---- h0 -> xh (recurrent h slots) ----
  for (int cid = tid; cid < 384; cid += 256) {
    const int b = cid & 7, j = cid >> 3;
#pragma unroll
    for (int l = 0; l < 3; ++l) xh[l][b][48 + j] = f2bf(h0[l*48 + j]);
  }
  // ---- c0 -> registers. Thread owns cell A (j=tid>>3, b=tid&7); threads<128 also cell B (j+32). ----
  const int jA = tid >> 3, bA = tid & 7;
  const int jB = 32 + ((tid & 127) >> 3), bB = tid & 7;  // clamped index: always in-bounds
  float cA[3], cB[3];
#pragma unroll
  for (int l = 0; l < 3; ++l) {
    cA[l] = c0[l*48 + jA];
    cB[l] = c0[l*48 + jB];   // value unused for tid>=128
  }
  __syncthreads();

  // ---- initial x-embed (inp = 0): x = bi * adjemb ----
  if (tid < 64) {
    const int b = tid >> 3, p = tid & 7;
#pragma unroll
    for (int q = 0; q < 6; ++q) {
      const int j = 6*p + q;
      xh[0][b][j] = f2bf(biS[j] * adjemb[b][j]);
    }
  }
  __syncthreads();

  // ---- main recurrence ----
  for (int t = 0; t < 128; ++t) {
#pragma unroll
    for (int l = 0; l < 3; ++l) {
      // --- gates = [x|h] @ W^T + bias (MFMA, M rows 8..15 duplicate 0..7) ---
      const unsigned short* xbase = &xh[l][lane & 7][0];
      const u16x8 a0 = *reinterpret_cast<const u16x8*>(xbase + 8*kg);
      const u16x8 a1 = *reinterpret_cast<const u16x8*>(xbase + 32 + 8*kg);
      const u16x8 a2 = *reinterpret_cast<const u16x8*>(xbase + 64 + 8*kg);
      f32x4 ac0 = {biasr[l][0], biasr[l][0], biasr[l][0], biasr[l][0]};
      f32x4 ac1 = {biasr[l][1], biasr[l][1], biasr[l][1], biasr[l][1]};
      f32x4 ac2 = {biasr[l][2], biasr[l][2], biasr[l][2], biasr[l][2]};
      ac0 = mfma16(a0, wf[l][0][0], ac0);
      ac1 = mfma16(a0, wf[l][0][1], ac1);
      ac2 = mfma16(a0, wf[l][0][2], ac2);
      ac0 = mfma16(a1, wf[l][1][0], ac0);
      ac1 = mfma16(a1, wf[l][1][1], ac1);
      ac2 = mfma16(a1, wf[l][1][2], ac2);
      ac0 = mfma16(a2, wf[l][2][0], ac0);
      ac1 = mfma16(a2, wf[l][2][1], ac1);
      ac2 = mfma16(a2, wf[l][2][2], ac2);
      if (lane < 32) {   // C rows 0..7 = real batches (col=lane&15 is gate, row=4*kg+reg is batch)
        const int g0 = 48*wv + col;
        *reinterpret_cast<f32x4*>(&gbuf[(g0     )*12 + 4*kg]) = ac0;
        *reinterpret_cast<f32x4*>(&gbuf[(g0 + 16)*12 + 4*kg]) = ac1;
        *reinterpret_cast<f32x4*>(&gbuf[(g0 + 32)*12 + 4*kg]) = ac2;
      }
      __syncthreads();
      // --- LSTM cell update (i,f,g,o rows = j, 48+j, 96+j, 144+j) ---
      {
        const float gi = gbuf[(      jA)*12 + bA];
        const float gf = gbuf[( 48 + jA)*12 + bA];
        const float gg = gbuf[( 96 + jA)*12 + bA];
        const float go = gbuf[(144 + jA)*12 + bA];
        const float iv = sigm(gi), fv = sigm(gf), gv = tanha(gg), ov = sigm(go);
        cA[l] = fv*cA[l] + iv*gv;
        const float h = ov * tanha(cA[l]);
        xh[l][bA][48 + jA] = f2bf(h);                       // recurrence for step t+1
        if (l < 2) xh[l+1][bA][jA] = f2bf(h); else h2f[bA][jA] = h;  // input of next layer / proj
      }
      if (tid < 128) {
        const float gi = gbuf[(      jB)*12 + bB];
        const float gf = gbuf[( 48 + jB)*12 + bB];
        const float gg = gbuf[( 96 + jB)*12 + bB];
        const float go = gbuf[(144 + jB)*12 + bB];
        const float iv = sigm(gi), fv = sigm(gf), gv = tanha(gg), ov = sigm(go);
        cB[l] = fv*cB[l] + iv*gv;
        const float h = ov * tanha(cB[l]);
        xh[l][bB][48 + jB] = f2bf(h);
        if (l < 2) xh[l+1][bB][jB] = f2bf(h); else h2f[bB][jB] = h;
      }
      __syncthreads();
    }
    // --- projection + sample + next-step x-embed (wave 0 only) ---
    if (tid < 64) {
      const int b = tid >> 3, p = tid & 7;
      float s = 0.f;
#pragma unroll
      for (int q = 0; q < 6; ++q) s += h2f[b][6*p + q] * WpS[6*p + q];
      s += __shfl_xor(s, 1, 64);
      s += __shfl_xor(s, 2, 64);
      s += __shfl_xor(s, 4, 64);        // all 8 lanes of the b-group now hold the full dot
      const float samp = (s + bpS + epsrow[b][t]) * adjrow[b][t];
      if (p == 0) out[(size_t)(b0 + b)*128 + t] = samp;
      // x = (samp*Wi + bi) * adjemb  -> layer-0 input for step t+1
#pragma unroll
      for (int q = 0; q < 6; ++q) {
        const int j = 6*p + q;
        xh[0][b][j] = f2bf((samp*WiS[j] + biS[j]) * adjemb[b][j]);
      }
    }
    __syncthreads();
  }
}

extern "C" void kernel_launch(void* const* d_in, const int* in_sizes, int n_in,
                              void* d_out, int out_size, void* d_ws, size_t ws_size,
                              hipStream_t stream) {
  const float* adj = (const float*)d_in[0];
  const float* eps = (const float*)d_in[1];
  const float* Wi  = (const float*)d_in[2];
  const float* bi  = (const float*)d_in[3];
  const float* Wa  = (const float*)d_in[4];
  const float* ba  = (const float*)d_in[5];
  const float* Wp  = (const float*)d_in[6];
  const float* bp  = (const float*)d_in[7];
  const float* Wih = (const float*)d_in[8];
  const float* Whh = (const float*)d_in[9];
  const float* bih = (const float*)d_in[10];
  const float* bhh = (const float*)d_in[11];
  const float* h0  = (const float*)d_in[12];
  const float* c0  = (const float*)d_in[13];

  lstm_fused<<<dim3(2048/8), dim3(256), 0, stream>>>(
      adj, eps, Wi, bi, Wa, ba, Wp, bp, Wih, Whh, bih, bhh, h0, c0, (float*)d_out);
}

// Round 2
// 238.203 us; speedup vs baseline: 1.0121x; 1.0121x over previous
//
#include <hip/hip_runtime.h>
#include <hip/hip_bf16.h>

// B=2048, T=128, H=48, L=3. Gates G=192, K=2H=96.
// One WG (256 thr, 4 waves) per 4 batches -> 512 WGs = 2 WGs/CU (latency hiding).
// Weights (bf16 B-fragments) live in registers; x|h in LDS (bf16); c in fp32 regs.

using bf16x8 = __attribute__((ext_vector_type(8))) __bf16;
using u16x8  = __attribute__((ext_vector_type(8))) unsigned short;
using f32x4  = __attribute__((ext_vector_type(4))) float;

__device__ __forceinline__ float fexp2(float x){ return __builtin_amdgcn_exp2f(x); }
__device__ __forceinline__ float frcp (float x){ return __builtin_amdgcn_rcpf(x); }
__device__ __forceinline__ float sigm (float x){ return frcp(1.f + fexp2(-1.44269504f*x)); }
__device__ __forceinline__ float tanha(float x){ return 1.f - 2.f*frcp(1.f + fexp2(2.88539008f*x)); }

__device__ __forceinline__ unsigned short f2bf(float x){
  unsigned u = __float_as_uint(x);
  return (unsigned short)((u + 0x7FFFu + ((u>>16)&1u)) >> 16);  // RNE
}

__device__ __forceinline__ f32x4 mfma16(u16x8 a, u16x8 b, f32x4 c){
  return __builtin_amdgcn_mfma_f32_16x16x32_bf16(
      __builtin_bit_cast(bf16x8, a), __builtin_bit_cast(bf16x8, b), c, 0, 0, 0);
}

__global__ __launch_bounds__(256, 2) void lstm_fused(
    const float* __restrict__ adj, const float* __restrict__ eps,
    const float* __restrict__ Wi,  const float* __restrict__ bi,
    const float* __restrict__ Wa,  const float* __restrict__ ba,
    const float* __restrict__ Wp,  const float* __restrict__ bp,
    const float* __restrict__ Wih, const float* __restrict__ Whh,
    const float* __restrict__ bih, const float* __restrict__ bhh,
    const float* __restrict__ h0,  const float* __restrict__ c0,
    float* __restrict__ out)
{
  const int tid  = threadIdx.x;
  const int wv   = tid >> 6;       // wave 0..3: owns gate columns 48*wv .. 48*wv+47
  const int lane = tid & 63;
  const int col  = lane & 15;      // MFMA n (gate) index
  const int kg   = lane >> 4;      // k-group 0..3
  const int b0   = blockIdx.x * 4; // this WG's batches

  __shared__ __align__(16) unsigned short xh[3][4][112]; // [layer][b][ x(0..47) | h(48..95) | pad ]
  __shared__ __align__(16) float gbuf[192*12];           // gates fp32: [gate][b(4), pad to 12]
  __shared__ float adjrow[4][128];
  __shared__ float epsrow[4][128];
  __shared__ float adjemb[4][48];
  __shared__ float h2f[4][52];
  __shared__ float WiS[48], biS[48], WpS[48];
  __shared__ float bpS;

  // ---- weight B-fragments -> registers (W^T combined [Wih|Whh], bf16) ----
  u16x8 wf[3][3][3];   // [layer][ktile][ntile]
  float biasr[3][3];   // bih+bhh per (layer, ntile) for this lane's column
#pragma unroll
  for (int l = 0; l < 3; ++l) {
#pragma unroll
    for (int kk = 0; kk < 3; ++kk) {
      const int k0 = 32*kk + 8*kg;                 // never straddles the 48 boundary
#pragma unroll
      for (int nt = 0; nt < 3; ++nt) {
        const int g = 48*wv + 16*nt + col;
        const float* src = (k0 < 48) ? (Wih + ((l*192 + g)*48 + k0))
                                     : (Whh + ((l*192 + g)*48 + (k0 - 48)));
        float4 p0 = *reinterpret_cast<const float4*>(src);
        float4 p1 = *reinterpret_cast<const float4*>(src + 4);
        u16x8 f;
        f[0]=f2bf(p0.x); f[1]=f2bf(p0.y); f[2]=f2bf(p0.z); f[3]=f2bf(p0.w);
        f[4]=f2bf(p1.x); f[5]=f2bf(p1.y); f[6]=f2bf(p1.z); f[7]=f2bf(p1.w);
        wf[l][kk][nt] = f;
      }
    }
#pragma unroll
    for (int nt = 0; nt < 3; ++nt) {
      const int g = 48*wv + 16*nt + col;
      biasr[l][nt] = bih[l*192 + g] + bhh[l*192 + g];
    }
  }

  // ---- stage adj/eps rows (4x128 each) + small vectors ----
  if (tid < 128)
    reinterpret_cast<float4*>(&adjrow[0][0])[tid] =
        reinterpret_cast<const float4*>(adj + (size_t)b0*128)[tid];
  else
    reinterpret_cast<float4*>(&epsrow[0][0])[tid-128] =
        reinterpret_cast<const float4*>(eps + (size_t)b0*128)[tid-128];
  if (tid < 48) { WiS[tid] = Wi[tid]; biS[tid] = bi[tid]; WpS[tid] = Wp[tid]; }
  if (tid == 0) bpS = bp[0];
  __syncthreads();

  // ---- per-thread cell ownership: tid<192 owns (j = tid>>2, b = tid&3) ----
  const int jC = tid >> 2, bC = tid & 3;
  float cc[3];

  if (tid < 192) {
    // adj embedding (constant across steps)
    float s = ba[jC];
    const float* wrow = Wa + jC*128;
    for (int t = 0; t < 128; ++t) s += adjrow[bC][t] * wrow[t];
    adjemb[bC][jC] = s;
    // h0 / c0
#pragma unroll
    for (int l = 0; l < 3; ++l) {
      xh[l][bC][48 + jC] = f2bf(h0[l*48 + jC]);
      cc[l] = c0[l*48 + jC];
    }
    // initial x-embed (inp = 0): x = bi * adjemb
    xh[0][bC][jC] = f2bf(biS[jC] * s);
  }
  __syncthreads();

  // ---- main recurrence ----
  for (int t = 0; t < 128; ++t) {
#pragma unroll
    for (int l = 0; l < 3; ++l) {
      // --- gates = [x|h] @ W^T + bias (MFMA, M rows 4..15 duplicate 0..3) ---
      const unsigned short* xbase = &xh[l][lane & 3][0];
      const u16x8 a0 = *reinterpret_cast<const u16x8*>(xbase + 8*kg);
      const u16x8 a1 = *reinterpret_cast<const u16x8*>(xbase + 32 + 8*kg);
      const u16x8 a2 = *reinterpret_cast<const u16x8*>(xbase + 64 + 8*kg);
      f32x4 ac0 = {biasr[l][0], biasr[l][0], biasr[l][0], biasr[l][0]};
      f32x4 ac1 = {biasr[l][1], biasr[l][1], biasr[l][1], biasr[l][1]};
      f32x4 ac2 = {biasr[l][2], biasr[l][2], biasr[l][2], biasr[l][2]};
      ac0 = mfma16(a0, wf[l][0][0], ac0);
      ac1 = mfma16(a0, wf[l][0][1], ac1);
      ac2 = mfma16(a0, wf[l][0][2], ac2);
      ac0 = mfma16(a1, wf[l][1][0], ac0);
      ac1 = mfma16(a1, wf[l][1][1], ac1);
      ac2 = mfma16(a1, wf[l][1][2], ac2);
      ac0 = mfma16(a2, wf[l][2][0], ac0);
      ac1 = mfma16(a2, wf[l][2][1], ac1);
      ac2 = mfma16(a2, wf[l][2][2], ac2);
      if (kg == 0) {   // C rows 0..3 (= batches 0..3) live in regs 0..3 of lanes 0..15
        const int g0 = 48*wv + col;
        *reinterpret_cast<f32x4*>(&gbuf[(g0     )*12]) = ac0;
        *reinterpret_cast<f32x4*>(&gbuf[(g0 + 16)*12]) = ac1;
        *reinterpret_cast<f32x4*>(&gbuf[(g0 + 32)*12]) = ac2;
      }
      __syncthreads();
      // --- LSTM cell update (i,f,g,o rows = j, 48+j, 96+j, 144+j) ---
      if (tid < 192) {
        const float gi = gbuf[(      jC)*12 + bC];
        const float gf = gbuf[( 48 + jC)*12 + bC];
        const float gg = gbuf[( 96 + jC)*12 + bC];
        const float go = gbuf[(144 + jC)*12 + bC];
        const float iv = sigm(gi), fv = sigm(gf), gv = tanha(gg), ov = sigm(go);
        cc[l] = fv*cc[l] + iv*gv;
        const float h = ov * tanha(cc[l]);
        xh[l][bC][48 + jC] = f2bf(h);                       // recurrence for step t+1
        if (l < 2) xh[l+1][bC][jC] = f2bf(h); else h2f[bC][jC] = h;
      }
      __syncthreads();
    }
    // --- projection + sample + next-step x-embed (lanes 0..31 of wave 0) ---
    if (tid < 32) {
      const int b = tid >> 3, p = tid & 7;
      float s = 0.f;
#pragma unroll
      for (int q = 0; q < 6; ++q) s += h2f[b][6*p + q] * WpS[6*p + q];
      s += __shfl_xor(s, 1, 64);
      s += __shfl_xor(s, 2, 64);
      s += __shfl_xor(s, 4, 64);        // all 8 lanes of the b-group hold the full dot
      const float samp = (s + bpS + epsrow[b][t]) * adjrow[b][t];
      if (p == 0) out[(size_t)(b0 + b)*128 + t] = samp;
      // x = (samp*Wi + bi) * adjemb  -> layer-0 input for step t+1
#pragma unroll
      for (int q = 0; q < 6; ++q) {
        const int j = 6*p + q;
        xh[0][b][j] = f2bf((samp*WiS[j] + biS[j]) * adjemb[b][j]);
      }
    }
    __syncthreads();
  }
}

extern "C" void kernel_launch(void* const* d_in, const int* in_sizes, int n_in,
                              void* d_out, int out_size, void* d_ws, size_t ws_size,
                              hipStream_t stream) {
  const float* adj = (const float*)d_in[0];
  const float* eps = (const float*)d_in[1];
  const float* Wi  = (const float*)d_in[2];
  const float* bi  = (const float*)d_in[3];
  const float* Wa  = (const float*)d_in[4];
  const float* ba  = (const float*)d_in[5];
  const float* Wp  = (const float*)d_in[6];
  const float* bp  = (const float*)d_in[7];
  const float* Wih = (const float*)d_in[8];
  const float* Whh = (const float*)d_in[9];
  const float* bih = (const float*)d_in[10];
  const float* bhh = (const float*)d_in[11];
  const float* h0  = (const float*)d_in[12];
  const float* c0  = (const float*)d_in[13];

  lstm_fused<<<dim3(2048/4), dim3(256), 0, stream>>>(
      adj, eps, Wi, bi, Wa, ba, Wp, bp, Wih, Whh, bih, bhh, h0, c0, (float*)d_out);
}